// Round 2
// baseline (468.690 us; speedup 1.0000x reference)
//
#include <hip/hip_runtime.h>

// PLIF: v[t] = zero-reset( v[t-1]*decay + x[t] ), reset at v >= 1.0.
// T=16, spatial = N*C*H*W = 4194304 elements -> 256 MiB in + 256 MiB out.
//
// Round-2 structure: t-major per thread. Each thread owns ONE float4 column
// and issues ALL 16 timestep loads up front (16 KB in flight per wave,
// ~16x the MLP of the t-sequenced version), pinned with sched_barrier(0)
// so the compiler cannot sink them back into the scan (round-1 failure:
// VGPR=28 proved the prefetch got collapsed). The scan then retires one
// load per step (vmcnt(15..0)); stores are always younger than every
// pending load, so no load-use wait chains behind a store-ack.
//
// t-offsets are wave-uniform -> the 16 load addresses share one VGPR
// offset + scalar base bumps; register cost is dominated by the 16
// float4 x-buffers (64 VGPRs). ~85 VGPR -> 6 waves/SIMD, plenty.

#define T_STEPS 16
#define V_THRESHOLD 1.0f

typedef float f32x4 __attribute__((ext_vector_type(4)));

__global__ __launch_bounds__(256) void plif_kernel(
    const f32x4* __restrict__ x,      // [T, SPATIAL/4]
    const float* __restrict__ decay,  // [1]
    f32x4*       __restrict__ out,    // [T, SPATIAL/4]
    long long    stride4)             // SPATIAL/4
{
    const long long col = (long long)blockIdx.x * blockDim.x + threadIdx.x;
    if (col >= stride4) return;
    const float d = decay[0];

    // ---- Phase 1: issue all T loads back-to-back (independent addresses).
    f32x4 xs[T_STEPS];
#pragma unroll
    for (int t = 0; t < T_STEPS; ++t)
        xs[t] = x[col + (long long)t * stride4];

    // Forbid the scheduler from sinking any load below this point.
    __builtin_amdgcn_sched_barrier(0);

    // ---- Phase 2: register scan; each step consumes the next load result.
    f32x4 v = (f32x4)0.f;
    long long off = col;
#pragma unroll
    for (int t = 0; t < T_STEPS; ++t) {
        const f32x4 xv = xs[t];
        v.x = fmaf(v.x, d, xv.x); if (v.x >= V_THRESHOLD) v.x = 0.f;
        v.y = fmaf(v.y, d, xv.y); if (v.y >= V_THRESHOLD) v.y = 0.f;
        v.z = fmaf(v.z, d, xv.z); if (v.z >= V_THRESHOLD) v.z = 0.f;
        v.w = fmaf(v.w, d, xv.w); if (v.w >= V_THRESHOLD) v.w = 0.f;
        __builtin_nontemporal_store(v, &out[off]);
        off += stride4;
    }
}

extern "C" void kernel_launch(void* const* d_in, const int* in_sizes, int n_in,
                              void* d_out, int out_size, void* d_ws, size_t ws_size,
                              hipStream_t stream) {
    const float* x     = (const float*)d_in[0];   // [T,N,C,H,W] fp32
    const float* decay = (const float*)d_in[1];   // [1] fp32
    float* out         = (float*)d_out;           // [T,N,C,H,W] fp32

    const long long total   = in_sizes[0];        // T * SPATIAL
    const long long spatial = total / T_STEPS;    // 4194304
    const long long stride4 = spatial / 4;        // 1048576 float4/timestep

    const int block = 256;
    const int grid  = (int)((stride4 + block - 1) / block);  // 4096

    plif_kernel<<<grid, block, 0, stream>>>(
        (const f32x4*)x, decay, (f32x4*)out, stride4);
}

// Round 3
// 465.493 us; speedup vs baseline: 1.0069x; 1.0069x over previous
//
#include <hip/hip_runtime.h>

// PLIF: v[t] = zero-reset( v[t-1]*decay + x[t] ), reset at v >= 1.0.
// T=16, spatial = N*C*H*W = 4194304 elements -> 256 MiB in + 256 MiB out.
//
// Round-3: same t-major structure as round 2, but the 16-deep load pipeline
// is pinned with a DATA DEPENDENCE, not a scheduling hint. Rounds 1-2 both
// failed because the compiler sank the prefetch loads back to their uses
// (VGPR_Count 28/36 < the 64 needed for 16 live float4 buffers):
// sched_barrier(0) is IntrNoMem, so IR-level sinking legally crossed it.
// Here each loaded value is passed through a volatile empty asm with a
// tied "+v" operand placed between load phase and scan phase. The asm
// *consumes* the value, so all 16 loads must be materialized there at
// every compiler stage. Consequences:
//   - 16 x 16 B = 16 KB in flight per wave (vs ~2 KB before).
//   - compiler-inserted waits become vmcnt(15) per step: stores issued in
//     the scan are always YOUNGER than every pending load, so a load-use
//     wait never drains a store-ack (the round-0/1/2 serialization).

#define T_STEPS 16
#define V_THRESHOLD 1.0f

typedef float f32x4 __attribute__((ext_vector_type(4)));

__global__ __launch_bounds__(256) void plif_kernel(
    const f32x4* __restrict__ x,      // [T, SPATIAL/4]
    const float* __restrict__ decay,  // [1]
    f32x4*       __restrict__ out,    // [T, SPATIAL/4]
    long long    stride4)             // SPATIAL/4
{
    const long long col = (long long)blockIdx.x * blockDim.x + threadIdx.x;
    if (col >= stride4) return;
    const float d = decay[0];

    // ---- Phase 1: issue all T loads back-to-back (independent addresses).
    f32x4 xs[T_STEPS];
#pragma unroll
    for (int t = 0; t < T_STEPS; ++t)
        xs[t] = x[col + (long long)t * stride4];

    // ---- Pin: hard data-dependence fence. Every xs[t] must live in VGPRs
    // HERE, so no load can be sunk below this point (at IR or MI level).
#pragma unroll
    for (int t = 0; t < T_STEPS; ++t)
        asm volatile("" : "+v"(xs[t]));

    // ---- Phase 2: register scan; step t consumes load t (vmcnt(15)).
    f32x4 v = (f32x4)0.f;
    long long off = col;
#pragma unroll
    for (int t = 0; t < T_STEPS; ++t) {
        const f32x4 xv = xs[t];
        v.x = fmaf(v.x, d, xv.x); if (v.x >= V_THRESHOLD) v.x = 0.f;
        v.y = fmaf(v.y, d, xv.y); if (v.y >= V_THRESHOLD) v.y = 0.f;
        v.z = fmaf(v.z, d, xv.z); if (v.z >= V_THRESHOLD) v.z = 0.f;
        v.w = fmaf(v.w, d, xv.w); if (v.w >= V_THRESHOLD) v.w = 0.f;
        __builtin_nontemporal_store(v, &out[off]);
        off += stride4;
    }
}

extern "C" void kernel_launch(void* const* d_in, const int* in_sizes, int n_in,
                              void* d_out, int out_size, void* d_ws, size_t ws_size,
                              hipStream_t stream) {
    const float* x     = (const float*)d_in[0];   // [T,N,C,H,W] fp32
    const float* decay = (const float*)d_in[1];   // [1] fp32
    float* out         = (float*)d_out;           // [T,N,C,H,W] fp32

    const long long total   = in_sizes[0];        // T * SPATIAL
    const long long spatial = total / T_STEPS;    // 4194304
    const long long stride4 = spatial / 4;        // 1048576 float4/timestep

    const int block = 256;
    const int grid  = (int)((stride4 + block - 1) / block);  // 4096

    plif_kernel<<<grid, block, 0, stream>>>(
        (const f32x4*)x, decay, (f32x4*)out, stride4);
}